// Round 1
// 6720.141 us; speedup vs baseline: 4.3099x; 4.3099x over previous
//
#include <hip/hip_runtime.h>
#include <cstdint>
#include <cstddef>

#define BB   128
#define IN   1024
#define HID  4096
#define OUTN 1024
#define TSTEPS 100
#define KC   384   // OpenBLAS SGEMM_DEFAULT_Q — panel structure must be preserved exactly

// ---------------- naive transpose: dst[c*R + r] = src[r*C + c] ----------------
__global__ __launch_bounds__(256) void ntrans_k(const float* __restrict__ src,
                                                float* __restrict__ dst,
                                                int R, int C) {
  int idx = blockIdx.x * 256 + threadIdx.x;   // grid sized exactly R*C/256
  int r = idx / C;
  int c = idx - r * C;
  dst[(size_t)c * R + r] = src[idx];
}

// f32 LIF exactly mirroring the reference op order (no FMA contraction).
__device__ __forceinline__ unsigned char lif_f32(float I, float& v, float& r) {
  bool active = I > 0.0f;
  bool refrac = r > 0.0f;
  float vi = __fadd_rn(__fmul_rn(v, 0.95f), I);
  bool fired = active && !refrac && (vi >= 1.0f);
  float vn = !active ? v : ((refrac || fired) ? 0.0f : vi);
  float rn = !active ? r : (refrac ? (r - 1.0f) : (fired ? 2.0f : r));
  v = vn; r = rn;
  return fired ? (unsigned char)1 : (unsigned char)0;
}

// ---------------- encode: one thread per (b,i), in-place refractory ----------------
__global__ __launch_bounds__(256) void encode_k(const float* __restrict__ noise_t,
                                                const float* __restrict__ x,
                                                float* __restrict__ rin,
                                                unsigned char* __restrict__ in_spk) {
  int gi = blockIdx.x * 256 + threadIdx.x;    // gi = b*IN + i, grid = BB*IN/256
  float p = __fmul_rn(x[gi], 100.0f);
  p = fminf(fmaxf(p, 0.0f), 100.0f);
  p = __fmul_rn(p, 0.001f);
  bool s = noise_t[gi] < p;                   // Bernoulli encode (strict <)
  float r = rin[gi];
  bool refrac = r > 0.0f;
  bool fired = s && !refrac;                  // input-layer v == 0 always (proven)
  rin[gi] = !s ? r : (refrac ? (r - 1.0f) : 2.0f);
  in_spk[gi] = fired ? 1 : 0;
}

// Block-wide (256 threads) exclusive scan helper pieces are inlined in the two
// consumer kernels below (wave=64 shfl scan + 4-entry LDS wave-sum combine).

// ---------------- hidden layer: in-block spike compaction + sparse panel sum ------
// Bit-exactness: within each KC panel the gated ascending-k adds are identical to
// iterating only the spiking k in ascending order (skipped adds were no-ops).
// Panels combined via one rounded add each, exactly as before.
__global__ __launch_bounds__(256) void hidden_k(const unsigned char* __restrict__ in_spk,
                                                const float* __restrict__ W1T,
                                                float* __restrict__ v_h,
                                                float* __restrict__ r_h,
                                                unsigned char* __restrict__ hid_spk) {
  int tid = threadIdx.x;
  int h = blockIdx.x * 256 + tid;
  int b = blockIdx.y;
  __shared__ unsigned short s_idx[IN];   // compacted ascending spike indices
  __shared__ int s_off[4];               // panel start offsets: 0, <384, <768, total
  __shared__ int wsum[4];

  // each thread owns k in [tid*4, tid*4+4)
  unsigned u = *reinterpret_cast<const unsigned*>(in_spk + (size_t)b * IN + tid * 4);
  int f0 =  u        & 0xff;
  int f1 = (u >> 8)  & 0xff;
  int f2 = (u >> 16) & 0xff;
  int f3 = (u >> 24) & 0xff;
  int cnt = f0 + f1 + f2 + f3;

  // wave-inclusive scan (64 lanes) then cross-wave combine
  int lane = tid & 63, wv = tid >> 6;
  int inc = cnt;
  #pragma unroll
  for (int d = 1; d < 64; d <<= 1) {
    int nn = __shfl_up(inc, d, 64);
    if (lane >= d) inc += nn;
  }
  if (lane == 63) wsum[wv] = inc;
  __syncthreads();
  int wbase = 0;
  #pragma unroll
  for (int w = 0; w < 4; w++) if (w < wv) wbase += wsum[w];
  int excl = wbase + inc - cnt;

  int o = excl, kb = tid * 4;
  if (f0) s_idx[o++] = (unsigned short)(kb);
  if (f1) s_idx[o++] = (unsigned short)(kb + 1);
  if (f2) s_idx[o++] = (unsigned short)(kb + 2);
  if (f3) s_idx[o++] = (unsigned short)(kb + 3);
  if (tid == 0)   s_off[0] = 0;          // panel k=0    starts at thread 0
  if (tid == 96)  s_off[1] = excl;       // panel k=384  starts at thread 96
  if (tid == 192) s_off[2] = excl;       // panel k=768  starts at thread 192
  if (tid == 255) s_off[3] = excl + cnt; // total spike count
  __syncthreads();

  float total = 0.0f;
  const float* Wc = W1T + h;
  #pragma unroll
  for (int p = 0; p < 3; p++) {
    int ks = s_off[p], ke = s_off[p + 1];
    float part = 0.0f;
    for (int k = ks; k < ke; k++) {
      int kk = s_idx[k];                               // uniform broadcast
      part = __fadd_rn(part, Wc[(size_t)kk * HID]);
    }
    total = __fadd_rn(total, part);   // first panel: rn(0+P0)=P0 exact
  }
  size_t idx = (size_t)b * HID + h;
  float v = v_h[idx], r = r_h[idx];
  hid_spk[idx] = lif_f32(total, v, r);
  v_h[idx] = v; r_h[idx] = r;
}

// ---------------- output layer: in-block compaction + sparse panel sum + LIF ------
__global__ __launch_bounds__(256) void out_k(const unsigned char* __restrict__ hid_spk,
                                             const float* __restrict__ W2T,
                                             float* __restrict__ v_o,
                                             float* __restrict__ r_o,
                                             float* __restrict__ out_acc) {
  int tid = threadIdx.x;
  int o = blockIdx.x * 256 + tid;
  int b = blockIdx.y;
  __shared__ unsigned short s_idx[HID];  // 8 KB
  __shared__ int s_off[12];              // 11 panels (4096 = 10*384 + 256) + total
  __shared__ int wsum[4];

  // each thread owns k in [tid*16, tid*16+16)
  uint4 u = *reinterpret_cast<const uint4*>(hid_spk + (size_t)b * HID + tid * 16);
  unsigned ww[4] = {u.x, u.y, u.z, u.w};
  int cnt = 0;
  #pragma unroll
  for (int j = 0; j < 16; j++) cnt += (ww[j >> 2] >> ((j & 3) * 8)) & 0xff;

  int lane = tid & 63, wv = tid >> 6;
  int inc = cnt;
  #pragma unroll
  for (int d = 1; d < 64; d <<= 1) {
    int nn = __shfl_up(inc, d, 64);
    if (lane >= d) inc += nn;
  }
  if (lane == 63) wsum[wv] = inc;
  __syncthreads();
  int wbase = 0;
  #pragma unroll
  for (int w = 0; w < 4; w++) if (w < wv) wbase += wsum[w];
  int excl = wbase + inc - cnt;

  int oo = excl, kb = tid * 16;
  #pragma unroll
  for (int j = 0; j < 16; j++) {
    if ((ww[j >> 2] >> ((j & 3) * 8)) & 0xff) s_idx[oo++] = (unsigned short)(kb + j);
  }
  // panel p starts at k = 384*p -> thread 24*p (384/16 == 24, exact)
  if ((tid % 24) == 0 && tid <= 240) s_off[tid / 24] = excl;
  if (tid == 255) s_off[11] = excl + cnt;
  __syncthreads();

  float total = 0.0f;
  const float* Wc = W2T + o;
  #pragma unroll
  for (int p = 0; p < 11; p++) {
    int ks = s_off[p], ke = s_off[p + 1];
    float part = 0.0f;
    for (int k = ks; k < ke; k++) {
      int kk = s_idx[k];
      part = __fadd_rn(part, Wc[(size_t)kk * OUTN]);
    }
    total = __fadd_rn(total, part);
  }
  size_t idx = (size_t)b * OUTN + o;
  float v = v_o[idx], r = r_o[idx];
  unsigned char fired = lif_f32(total, v, r);
  v_o[idx] = v; r_o[idx] = r;
  if (fired) out_acc[idx] = __fadd_rn(out_acc[idx], 1.0f);  // exact int count
}

// ---------------- STDP kernels (t % 10 == 0), f32 ----------------
__global__ void zero2_k(int* flags) { flags[0] = 0; flags[1] = 0; }

__global__ __launch_bounds__(256) void stats_k(
    const unsigned char* __restrict__ in_spk, const unsigned char* __restrict__ hid_spk,
    float* __restrict__ pre_m, float* __restrict__ post_m,
    float* __restrict__ tp, float* __restrict__ tn, int* __restrict__ flags) {
  int c = blockIdx.x * 256 + threadIdx.x;
  if (c < IN) {
    int i = c, cnt = 0;
    for (int b = 0; b < BB; b++) cnt += in_spk[(size_t)b * IN + i];
    float pm = __fdiv_rn((float)cnt, 128.0f);       // exact (pow2)
    pre_m[i] = pm;
    tp[i] = __fadd_rn(__fmul_rn(0.9f, tp[i]), pm);  // tp_n committed (stdp step)
    if (cnt > 0) atomicOr(flags + 0, 1);
  } else if (c < IN + HID) {
    int h = c - IN, cnt = 0;
    for (int b = 0; b < BB; b++) cnt += hid_spk[(size_t)b * HID + h];
    float pm = __fdiv_rn((float)cnt, 128.0f);
    post_m[h] = pm;
    tn[h] = __fadd_rn(__fmul_rn(0.9f, tn[h]), pm);
    if (cnt > 0) atomicOr(flags + 1, 1);
  }
}

__global__ __launch_bounds__(256) void apply_k(
    float* __restrict__ W1T,
    const float* __restrict__ tp, const float* __restrict__ tn,
    const float* __restrict__ pre_m, const float* __restrict__ post_m,
    const int* __restrict__ flags) {
  if (!(flags[0] && flags[1])) return;   // 'both' gate
  size_t idx = (size_t)blockIdx.x * 256 + threadIdx.x;  // i*HID + h layout
  int i = (int)(idx >> 12);
  int h = (int)(idx & 4095);
  float a  = __fmul_rn(tp[i], post_m[h]);     // tp already == tp_n
  float b2 = __fmul_rn(pre_m[i], tn[h]);      // tn already == tn_n
  float d  = __fmul_rn(0.001f, __fsub_rn(a, b2));
  float w  = __fadd_rn(W1T[idx], d);
  w = fminf(fmaxf(w, -1.0f), 1.0f);           // jnp.clip: max then min
  W1T[idx] = w;
}

__global__ __launch_bounds__(256) void scale_k(const float* __restrict__ acc,
                                               float* __restrict__ out) {
  int j = blockIdx.x * 256 + threadIdx.x;
  out[j] = __fdiv_rn(acc[j], 100.0f);
}

// ---------------- host launcher ----------------
extern "C" void kernel_launch(void* const* d_in, const int* in_sizes, int n_in,
                              void* d_out, int out_size, void* d_ws, size_t ws_size,
                              hipStream_t stream) {
  (void)in_sizes; (void)n_in; (void)out_size; (void)ws_size;
  const float* x     = (const float*)d_in[0];
  const float* W1    = (const float*)d_in[1];
  const float* W2    = (const float*)d_in[2];
  const float* noise = (const float*)d_in[3];

  char* ws = (char*)d_ws;
  size_t off = 0;
  auto alloc = [&](size_t bytes) -> char* {
    char* p = ws + off;
    off += (bytes + 255) & ~(size_t)255;
    return p;
  };
  float* W1T   = (float*)alloc((size_t)IN * HID * 4);     // 16 MB working copy (i-major)
  float* W2T   = (float*)alloc((size_t)HID * OUTN * 4);   // 16 MB (h-major)
  float* v_h   = (float*)alloc((size_t)BB * HID * 4);
  float* r_h   = (float*)alloc((size_t)BB * HID * 4);
  float* v_o   = (float*)alloc((size_t)BB * OUTN * 4);
  float* r_o   = (float*)alloc((size_t)BB * OUTN * 4);
  float* rin   = (float*)alloc((size_t)BB * IN * 4);      // in-place (one owner thread)
  float* acc   = (float*)alloc((size_t)BB * OUTN * 4);
  float* tp    = (float*)alloc((size_t)IN * 4);
  float* tn    = (float*)alloc((size_t)HID * 4);
  float* pre_m = (float*)alloc((size_t)IN * 4);
  float* post_m= (float*)alloc((size_t)HID * 4);
  unsigned char* in_spk  = (unsigned char*)alloc((size_t)BB * IN);
  unsigned char* hid_spk = (unsigned char*)alloc((size_t)BB * HID);
  int* flags   = (int*)alloc(2 * sizeof(int));

  // zero all state (ws is poisoned before every call)
  hipMemsetAsync(v_h, 0, (size_t)BB * HID * 4, stream);
  hipMemsetAsync(r_h, 0, (size_t)BB * HID * 4, stream);
  hipMemsetAsync(v_o, 0, (size_t)BB * OUTN * 4, stream);
  hipMemsetAsync(r_o, 0, (size_t)BB * OUTN * 4, stream);
  hipMemsetAsync(rin, 0, (size_t)BB * IN * 4, stream);
  hipMemsetAsync(acc, 0, (size_t)BB * OUTN * 4, stream);
  hipMemsetAsync(tp,  0, (size_t)IN * 4, stream);
  hipMemsetAsync(tn,  0, (size_t)HID * 4, stream);

  // W1 (HID x IN) -> W1T (IN x HID): R=HID, C=IN. W2 (OUTN x HID) -> W2T (HID x OUTN).
  ntrans_k<<<(HID * IN) / 256, 256, 0, stream>>>(W1, W1T, HID, IN);
  ntrans_k<<<(OUTN * HID) / 256, 256, 0, stream>>>(W2, W2T, OUTN, HID);

  for (int t = 0; t < TSTEPS; t++) {
    const float* nz = noise + (size_t)t * BB * IN;
    encode_k<<<(BB * IN) / 256, 256, 0, stream>>>(nz, x, rin, in_spk);
    hidden_k<<<dim3(HID / 256, BB), 256, 0, stream>>>(in_spk, W1T, v_h, r_h, hid_spk);
    out_k<<<dim3(OUTN / 256, BB), 256, 0, stream>>>(hid_spk, W2T, v_o, r_o, acc);
    if (t % 10 == 0) {
      zero2_k<<<1, 1, 0, stream>>>(flags);
      stats_k<<<(IN + HID + 255) / 256, 256, 0, stream>>>(in_spk, hid_spk,
                                                          pre_m, post_m, tp, tn, flags);
      apply_k<<<(IN * HID) / 256, 256, 0, stream>>>(W1T, tp, tn, pre_m, post_m, flags);
    }
  }
  scale_k<<<(BB * OUTN) / 256, 256, 0, stream>>>(acc, (float*)d_out);
}

// Round 2
// 3602.836 us; speedup vs baseline: 8.0389x; 1.8652x over previous
//
#include <hip/hip_runtime.h>
#include <cstdint>
#include <cstddef>

#define BB   128
#define IN   1024
#define HID  4096
#define OUTN 1024
#define TSTEPS 100
#define KC   384   // OpenBLAS SGEMM_DEFAULT_Q — panel structure must be preserved exactly

// ---------------- naive transpose: dst[c*R + r] = src[r*C + c] ----------------
__global__ __launch_bounds__(256) void ntrans_k(const float* __restrict__ src,
                                                float* __restrict__ dst,
                                                int R, int C) {
  int idx = blockIdx.x * 256 + threadIdx.x;   // grid sized exactly R*C/256
  int r = idx / C;
  int c = idx - r * C;
  dst[(size_t)c * R + r] = src[idx];
}

// f32 LIF exactly mirroring the reference op order (no FMA contraction).
__device__ __forceinline__ unsigned char lif_f32(float I, float& v, float& r) {
  bool active = I > 0.0f;
  bool refrac = r > 0.0f;
  float vi = __fadd_rn(__fmul_rn(v, 0.95f), I);
  bool fired = active && !refrac && (vi >= 1.0f);
  float vn = !active ? v : ((refrac || fired) ? 0.0f : vi);
  float rn = !active ? r : (refrac ? (r - 1.0f) : (fired ? 2.0f : r));
  v = vn; r = rn;
  return fired ? (unsigned char)1 : (unsigned char)0;
}

// ---------------- hidden layer: fused encode + compaction + sparse panel sum ------
// Encode is recomputed redundantly by all 16 blocks of a batch row (cheap: 4 elems
// per thread); block.x==0 commits rin state (ping-pong buffer, no read/write race)
// and the in_spk bytes needed by stats_k.
// Bit-exactness: within each KC panel the gated ascending-k adds are identical to
// iterating only the spiking k in ascending order (skipped adds were no-ops).
// Panels combined via one rounded add each, exactly as before. The 4-wide unroll
// only batches the loads; the adds remain in ascending-k order.
__global__ __launch_bounds__(256) void hidden_k(
    const float* __restrict__ noise_t, const float* __restrict__ x,
    const float* __restrict__ rin_in, float* __restrict__ rin_out,
    unsigned char* __restrict__ in_spk,
    const float* __restrict__ W1T,
    float* __restrict__ v_h, float* __restrict__ r_h,
    unsigned char* __restrict__ hid_spk) {
  int tid = threadIdx.x;
  int h = blockIdx.x * 256 + tid;
  int b = blockIdx.y;
  __shared__ unsigned short s_idx[IN];   // compacted ascending spike indices
  __shared__ int s_off[4];               // panel start offsets: 0, <384, <768, total
  __shared__ int wsum[4];

  // ---- fused encode: each thread owns k in [tid*4, tid*4+4) ----
  size_t ebase = (size_t)b * IN + (size_t)tid * 4;
  const float4 xv = *reinterpret_cast<const float4*>(x + ebase);
  const float4 nv = *reinterpret_cast<const float4*>(noise_t + ebase);
  const float4 rv = *reinterpret_cast<const float4*>(rin_in + ebase);
  float px[4] = {xv.x, xv.y, xv.z, xv.w};
  float pn[4] = {nv.x, nv.y, nv.z, nv.w};
  float pr[4] = {rv.x, rv.y, rv.z, rv.w};
  int f[4]; float rn[4];
  #pragma unroll
  for (int j = 0; j < 4; j++) {
    float p = __fmul_rn(px[j], 100.0f);
    p = fminf(fmaxf(p, 0.0f), 100.0f);
    p = __fmul_rn(p, 0.001f);
    bool s = pn[j] < p;                  // Bernoulli encode (strict <)
    bool refrac = pr[j] > 0.0f;
    bool fired = s && !refrac;           // input-layer v == 0 always (proven)
    rn[j] = !s ? pr[j] : (refrac ? (pr[j] - 1.0f) : 2.0f);
    f[j] = fired ? 1 : 0;
  }
  if (blockIdx.x == 0) {                 // single owner commits state
    *reinterpret_cast<float4*>(rin_out + ebase) = make_float4(rn[0], rn[1], rn[2], rn[3]);
    uchar4 sp; sp.x = (unsigned char)f[0]; sp.y = (unsigned char)f[1];
    sp.z = (unsigned char)f[2]; sp.w = (unsigned char)f[3];
    *reinterpret_cast<uchar4*>(in_spk + ebase) = sp;
  }
  int cnt = f[0] + f[1] + f[2] + f[3];

  // ---- block exclusive scan: wave-inclusive shfl scan + cross-wave combine ----
  int lane = tid & 63, wv = tid >> 6;
  int inc = cnt;
  #pragma unroll
  for (int d = 1; d < 64; d <<= 1) {
    int nn = __shfl_up(inc, d, 64);
    if (lane >= d) inc += nn;
  }
  if (lane == 63) wsum[wv] = inc;
  __syncthreads();
  int wbase = 0;
  #pragma unroll
  for (int w = 0; w < 4; w++) if (w < wv) wbase += wsum[w];
  int excl = wbase + inc - cnt;

  int o = excl, kb = tid * 4;
  if (f[0]) s_idx[o++] = (unsigned short)(kb);
  if (f[1]) s_idx[o++] = (unsigned short)(kb + 1);
  if (f[2]) s_idx[o++] = (unsigned short)(kb + 2);
  if (f[3]) s_idx[o++] = (unsigned short)(kb + 3);
  if (tid == 0)   s_off[0] = 0;          // panel k=0    starts at thread 0
  if (tid == 96)  s_off[1] = excl;       // panel k=384  starts at thread 96
  if (tid == 192) s_off[2] = excl;       // panel k=768  starts at thread 192
  if (tid == 255) s_off[3] = excl + cnt; // total spike count
  __syncthreads();

  float total = 0.0f;
  const float* Wc = W1T + h;
  #pragma unroll
  for (int p = 0; p < 3; p++) {
    int ks = s_off[p], ke = s_off[p + 1];
    float part = 0.0f;
    int k = ks;
    for (; k + 4 <= ke; k += 4) {        // batch 4 independent loads, ordered adds
      int k0 = s_idx[k], k1 = s_idx[k + 1], k2 = s_idx[k + 2], k3 = s_idx[k + 3];
      float w0 = Wc[(size_t)k0 * HID];
      float w1 = Wc[(size_t)k1 * HID];
      float w2 = Wc[(size_t)k2 * HID];
      float w3 = Wc[(size_t)k3 * HID];
      part = __fadd_rn(part, w0);
      part = __fadd_rn(part, w1);
      part = __fadd_rn(part, w2);
      part = __fadd_rn(part, w3);
    }
    for (; k < ke; k++) part = __fadd_rn(part, Wc[(size_t)s_idx[k] * HID]);
    total = __fadd_rn(total, part);      // first panel: rn(0+P0)=P0 exact
  }
  size_t idx = (size_t)b * HID + h;
  float v = v_h[idx], r = r_h[idx];
  hid_spk[idx] = lif_f32(total, v, r);
  v_h[idx] = v; r_h[idx] = r;
}

// ---------------- output layer: in-block compaction + sparse panel sum + LIF ------
__global__ __launch_bounds__(256) void out_k(const unsigned char* __restrict__ hid_spk,
                                             const float* __restrict__ W2T,
                                             float* __restrict__ v_o,
                                             float* __restrict__ r_o,
                                             float* __restrict__ out_acc) {
  int tid = threadIdx.x;
  int o = blockIdx.x * 256 + tid;
  int b = blockIdx.y;
  __shared__ unsigned short s_idx[HID];  // 8 KB
  __shared__ int s_off[12];              // 11 panels (4096 = 10*384 + 256) + total
  __shared__ int wsum[4];

  // each thread owns k in [tid*16, tid*16+16)
  uint4 u = *reinterpret_cast<const uint4*>(hid_spk + (size_t)b * HID + tid * 16);
  unsigned ww[4] = {u.x, u.y, u.z, u.w};
  int cnt = 0;
  #pragma unroll
  for (int j = 0; j < 16; j++) cnt += (ww[j >> 2] >> ((j & 3) * 8)) & 0xff;

  int lane = tid & 63, wv = tid >> 6;
  int inc = cnt;
  #pragma unroll
  for (int d = 1; d < 64; d <<= 1) {
    int nn = __shfl_up(inc, d, 64);
    if (lane >= d) inc += nn;
  }
  if (lane == 63) wsum[wv] = inc;
  __syncthreads();
  int wbase = 0;
  #pragma unroll
  for (int w = 0; w < 4; w++) if (w < wv) wbase += wsum[w];
  int excl = wbase + inc - cnt;

  int oo = excl, kb = tid * 16;
  #pragma unroll
  for (int j = 0; j < 16; j++) {
    if ((ww[j >> 2] >> ((j & 3) * 8)) & 0xff) s_idx[oo++] = (unsigned short)(kb + j);
  }
  // panel p starts at k = 384*p -> thread 24*p (384/16 == 24, exact)
  if ((tid % 24) == 0 && tid <= 240) s_off[tid / 24] = excl;
  if (tid == 255) s_off[11] = excl + cnt;
  __syncthreads();

  float total = 0.0f;
  const float* Wc = W2T + o;
  #pragma unroll
  for (int p = 0; p < 11; p++) {
    int ks = s_off[p], ke = s_off[p + 1];
    float part = 0.0f;
    int k = ks;
    for (; k + 8 <= ke; k += 8) {        // batch 8 independent loads, ordered adds
      int k0 = s_idx[k],     k1 = s_idx[k + 1], k2 = s_idx[k + 2], k3 = s_idx[k + 3];
      int k4 = s_idx[k + 4], k5 = s_idx[k + 5], k6 = s_idx[k + 6], k7 = s_idx[k + 7];
      float w0 = Wc[(size_t)k0 * OUTN];
      float w1 = Wc[(size_t)k1 * OUTN];
      float w2 = Wc[(size_t)k2 * OUTN];
      float w3 = Wc[(size_t)k3 * OUTN];
      float w4 = Wc[(size_t)k4 * OUTN];
      float w5 = Wc[(size_t)k5 * OUTN];
      float w6 = Wc[(size_t)k6 * OUTN];
      float w7 = Wc[(size_t)k7 * OUTN];
      part = __fadd_rn(part, w0);
      part = __fadd_rn(part, w1);
      part = __fadd_rn(part, w2);
      part = __fadd_rn(part, w3);
      part = __fadd_rn(part, w4);
      part = __fadd_rn(part, w5);
      part = __fadd_rn(part, w6);
      part = __fadd_rn(part, w7);
    }
    if (k + 4 <= ke) {
      int k0 = s_idx[k], k1 = s_idx[k + 1], k2 = s_idx[k + 2], k3 = s_idx[k + 3];
      float w0 = Wc[(size_t)k0 * OUTN];
      float w1 = Wc[(size_t)k1 * OUTN];
      float w2 = Wc[(size_t)k2 * OUTN];
      float w3 = Wc[(size_t)k3 * OUTN];
      part = __fadd_rn(part, w0);
      part = __fadd_rn(part, w1);
      part = __fadd_rn(part, w2);
      part = __fadd_rn(part, w3);
      k += 4;
    }
    for (; k < ke; k++) part = __fadd_rn(part, Wc[(size_t)s_idx[k] * OUTN]);
    total = __fadd_rn(total, part);
  }
  size_t idx = (size_t)b * OUTN + o;
  float v = v_o[idx], r = r_o[idx];
  unsigned char fired = lif_f32(total, v, r);
  v_o[idx] = v; r_o[idx] = r;
  if (fired) out_acc[idx] = __fadd_rn(out_acc[idx], 1.0f);  // exact int count
}

// ---------------- STDP kernels (t % 10 == 0), f32 ----------------
__global__ __launch_bounds__(256) void stats_k(
    const unsigned char* __restrict__ in_spk, const unsigned char* __restrict__ hid_spk,
    float* __restrict__ pre_m, float* __restrict__ post_m,
    float* __restrict__ tp, float* __restrict__ tn, int* __restrict__ flags) {
  int c = blockIdx.x * 256 + threadIdx.x;
  if (c < IN) {
    int i = c, cnt = 0;
    for (int b = 0; b < BB; b++) cnt += in_spk[(size_t)b * IN + i];
    float pm = __fdiv_rn((float)cnt, 128.0f);       // exact (pow2)
    pre_m[i] = pm;
    tp[i] = __fadd_rn(__fmul_rn(0.9f, tp[i]), pm);  // tp_n committed (stdp step)
    if (cnt > 0) atomicOr(flags + 0, 1);
  } else if (c < IN + HID) {
    int h = c - IN, cnt = 0;
    for (int b = 0; b < BB; b++) cnt += hid_spk[(size_t)b * HID + h];
    float pm = __fdiv_rn((float)cnt, 128.0f);
    post_m[h] = pm;
    tn[h] = __fadd_rn(__fmul_rn(0.9f, tn[h]), pm);
    if (cnt > 0) atomicOr(flags + 1, 1);
  }
}

__global__ __launch_bounds__(256) void apply_k(
    float* __restrict__ W1T,
    const float* __restrict__ tp, const float* __restrict__ tn,
    const float* __restrict__ pre_m, const float* __restrict__ post_m,
    const int* __restrict__ flags) {
  if (!(flags[0] && flags[1])) return;   // 'both' gate
  size_t idx = (size_t)blockIdx.x * 256 + threadIdx.x;  // i*HID + h layout
  int i = (int)(idx >> 12);
  int h = (int)(idx & 4095);
  float a  = __fmul_rn(tp[i], post_m[h]);     // tp already == tp_n
  float b2 = __fmul_rn(pre_m[i], tn[h]);      // tn already == tn_n
  float d  = __fmul_rn(0.001f, __fsub_rn(a, b2));
  float w  = __fadd_rn(W1T[idx], d);
  w = fminf(fmaxf(w, -1.0f), 1.0f);           // jnp.clip: max then min
  W1T[idx] = w;
}

__global__ __launch_bounds__(256) void scale_k(const float* __restrict__ acc,
                                               float* __restrict__ out) {
  int j = blockIdx.x * 256 + threadIdx.x;
  out[j] = __fdiv_rn(acc[j], 100.0f);
}

// ---------------- host launcher ----------------
extern "C" void kernel_launch(void* const* d_in, const int* in_sizes, int n_in,
                              void* d_out, int out_size, void* d_ws, size_t ws_size,
                              hipStream_t stream) {
  (void)in_sizes; (void)n_in; (void)out_size; (void)ws_size;
  const float* x     = (const float*)d_in[0];
  const float* W1    = (const float*)d_in[1];
  const float* W2    = (const float*)d_in[2];
  const float* noise = (const float*)d_in[3];

  char* ws = (char*)d_ws;
  size_t off = 0;
  auto alloc = [&](size_t bytes) -> char* {
    char* p = ws + off;
    off += (bytes + 255) & ~(size_t)255;
    return p;
  };
  float* W1T   = (float*)alloc((size_t)IN * HID * 4);     // 16 MB working copy (i-major)
  float* W2T   = (float*)alloc((size_t)HID * OUTN * 4);   // 16 MB (h-major)
  float* v_h   = (float*)alloc((size_t)BB * HID * 4);
  float* r_h   = (float*)alloc((size_t)BB * HID * 4);
  float* v_o   = (float*)alloc((size_t)BB * OUTN * 4);
  float* r_o   = (float*)alloc((size_t)BB * OUTN * 4);
  float* rinA  = (float*)alloc((size_t)BB * IN * 4);      // ping-pong refractory state
  float* rinB  = (float*)alloc((size_t)BB * IN * 4);
  float* acc   = (float*)alloc((size_t)BB * OUTN * 4);
  float* tp    = (float*)alloc((size_t)IN * 4);
  float* tn    = (float*)alloc((size_t)HID * 4);
  float* pre_m = (float*)alloc((size_t)IN * 4);
  float* post_m= (float*)alloc((size_t)HID * 4);
  unsigned char* in_spk  = (unsigned char*)alloc((size_t)BB * IN);
  unsigned char* hid_spk = (unsigned char*)alloc((size_t)BB * HID);
  int* flags   = (int*)alloc(2 * 10 * sizeof(int));       // per-STDP-step slots

  // zero all state (ws is poisoned before every call)
  hipMemsetAsync(v_h, 0, (size_t)BB * HID * 4, stream);
  hipMemsetAsync(r_h, 0, (size_t)BB * HID * 4, stream);
  hipMemsetAsync(v_o, 0, (size_t)BB * OUTN * 4, stream);
  hipMemsetAsync(r_o, 0, (size_t)BB * OUTN * 4, stream);
  hipMemsetAsync(rinA, 0, (size_t)BB * IN * 4, stream);
  hipMemsetAsync(acc, 0, (size_t)BB * OUTN * 4, stream);
  hipMemsetAsync(tp,  0, (size_t)IN * 4, stream);
  hipMemsetAsync(tn,  0, (size_t)HID * 4, stream);
  hipMemsetAsync(flags, 0, 2 * 10 * sizeof(int), stream);

  // W1 (HID x IN) -> W1T (IN x HID): R=HID, C=IN. W2 (OUTN x HID) -> W2T (HID x OUTN).
  ntrans_k<<<(HID * IN) / 256, 256, 0, stream>>>(W1, W1T, HID, IN);
  ntrans_k<<<(OUTN * HID) / 256, 256, 0, stream>>>(W2, W2T, OUTN, HID);

  float* rin_in = rinA;
  float* rin_out = rinB;
  for (int t = 0; t < TSTEPS; t++) {
    const float* nz = noise + (size_t)t * BB * IN;
    hidden_k<<<dim3(HID / 256, BB), 256, 0, stream>>>(nz, x, rin_in, rin_out, in_spk,
                                                      W1T, v_h, r_h, hid_spk);
    out_k<<<dim3(OUTN / 256, BB), 256, 0, stream>>>(hid_spk, W2T, v_o, r_o, acc);
    if (t % 10 == 0) {
      int* fl = flags + 2 * (t / 10);
      stats_k<<<(IN + HID + 255) / 256, 256, 0, stream>>>(in_spk, hid_spk,
                                                          pre_m, post_m, tp, tn, fl);
      apply_k<<<(IN * HID) / 256, 256, 0, stream>>>(W1T, tp, tn, pre_m, post_m, fl);
    }
    float* tmpp = rin_in; rin_in = rin_out; rin_out = tmpp;
  }
  scale_k<<<(BB * OUTN) / 256, 256, 0, stream>>>(acc, (float*)d_out);
}